// Round 2
// baseline (1065.124 us; speedup 1.0000x reference)
//
#include <hip/hip_runtime.h>

// Problem constants
#define QD   1280
#define CD   768
#define NH   8
#define NN   2
#define ZZ   2
#define RR   8
#define BFB  16
#define SS   4096
#define DH   160           // QD/NH
#define TT   4             // NN*ZZ
#define OO   32            // NH*TT

typedef __attribute__((ext_vector_type(4))) float f32x4;

// ---------------------------------------------------------------------------
// K1: K/V = lora(ctx3d, W, A, B).  ctx3d[b,t,c] = context[b, t>>1, c] + pe[t&1, c]
// grid (5 jtiles, 4 t, 16 b), 256 thr. Outputs Kf/Vf [16][4][1280] f32.
// ---------------------------------------------------------------------------
__global__ __launch_bounds__(256) void kv_kernel(
    const float* __restrict__ ctx, const float* __restrict__ pe,
    const float* __restrict__ Wk, const float* __restrict__ Ak, const float* __restrict__ Bk,
    const float* __restrict__ Wv, const float* __restrict__ Av, const float* __restrict__ Bv,
    float* __restrict__ Kf, float* __restrict__ Vf)
{
    const int jt = blockIdx.x, t = blockIdx.y, b = blockIdx.z;
    const int n = t >> 1, z = t & 1;
    const int tid = threadIdx.x;
    __shared__ float sctx[CD];
    __shared__ float sa[16];     // a_k[0..7], a_v[8..15]

    for (int c = tid; c < CD; c += 256)
        sctx[c] = ctx[(b * NN + n) * CD + c] + pe[z * CD + c];
    __syncthreads();

    const int wave = tid >> 6, lane = tid & 63;
    for (int q = 0; q < 4; q++) {
        const int idx = wave * 4 + q;                 // 0..15
        const float* Arow = (idx < 8 ? Ak : Av) + (idx & 7) * CD;
        float p = 0.f;
        for (int c = lane; c < CD; c += 64) p += sctx[c] * Arow[c];
        for (int off = 32; off; off >>= 1) p += __shfl_down(p, off);
        if (lane == 0) sa[idx] = p;
    }
    __syncthreads();

    const int j = jt * 256 + tid;
    float accK = 0.f, accV = 0.f;
    {
        f32x4 bk0 = *(const f32x4*)(Bk + j * RR);
        f32x4 bk1 = *(const f32x4*)(Bk + j * RR + 4);
        f32x4 bv0 = *(const f32x4*)(Bv + j * RR);
        f32x4 bv1 = *(const f32x4*)(Bv + j * RR + 4);
#pragma unroll
        for (int r = 0; r < 4; r++) {
            accK += sa[r] * bk0[r] + sa[r + 4] * bk1[r];
            accV += sa[8 + r] * bv0[r] + sa[12 + r] * bv1[r];
        }
    }
    const f32x4* wkrow = (const f32x4*)(Wk + j * CD);
    const f32x4* wvrow = (const f32x4*)(Wv + j * CD);
    for (int c4 = 0; c4 < CD / 4; c4++) {
        f32x4 wk = wkrow[c4], wv = wvrow[c4];
#pragma unroll
        for (int u = 0; u < 4; u++) {
            float xc = sctx[c4 * 4 + u];
            accK += xc * wk[u];
            accV += xc * wv[u];
        }
    }
    Kf[(b * TT + t) * QD + j] = accK;
    Vf[(b * TT + t) * QD + j] = accV;
}

// ---------------------------------------------------------------------------
// K2: P[b][k][ht] = sum_d Wq[h*160+d, k] * Kf[b,t, h*160+d]      (which==0)
//     VW[b][ht][j] = sum_d Vf[b,t, h*160+d] * Wout[j, h*160+d]   (which==1)
// grid (2 which, 32 ht, 16 b), 256 thr.
// ---------------------------------------------------------------------------
__global__ __launch_bounds__(256) void pvw_kernel(
    const float* __restrict__ Wq, const float* __restrict__ Wout,
    const float* __restrict__ Kf, const float* __restrict__ Vf,
    float* __restrict__ P, float* __restrict__ VW)
{
    const int which = blockIdx.x, ht = blockIdx.y, b = blockIdx.z;
    const int h = ht >> 2, t = ht & 3;
    const int tid = threadIdx.x;
    __shared__ float sv[DH];

    if (which == 0) {
        for (int d = tid; d < DH; d += 256) sv[d] = Kf[(b * TT + t) * QD + h * DH + d];
        __syncthreads();
        float acc[5] = {0.f, 0.f, 0.f, 0.f, 0.f};
        for (int d = 0; d < DH; d++) {
            float kd = sv[d];
            const float* wqrow = Wq + (h * DH + d) * QD;
#pragma unroll
            for (int i = 0; i < 5; i++) acc[i] += kd * wqrow[tid + 256 * i];
        }
#pragma unroll
        for (int i = 0; i < 5; i++)
            P[(b * QD + tid + 256 * i) * OO + ht] = acc[i];
    } else {
        for (int d = tid; d < DH; d += 256) sv[d] = Vf[(b * TT + t) * QD + h * DH + d];
        __syncthreads();
        float acc[5] = {0.f, 0.f, 0.f, 0.f, 0.f};
        for (int d4 = 0; d4 < DH / 4; d4++) {
#pragma unroll
            for (int i = 0; i < 5; i++) {
                int j = tid + 256 * i;
                f32x4 w = *(const f32x4*)(Wout + j * QD + h * DH + d4 * 4);
#pragma unroll
                for (int u = 0; u < 4; u++) acc[i] += sv[d4 * 4 + u] * w[u];
            }
        }
#pragma unroll
        for (int i = 0; i < 5; i++)
            VW[(b * OO + ht) * QD + tid + 256 * i] = acc[i];
    }
}

// ---------------------------------------------------------------------------
// K3: scores -> sigmoid -> transmittance -> weights.
// grid (32 s-tiles of 128 rows, 16 b), 256 thr.
// Thread (o = tid&31, c = tid>>5) keeps P[b][c*160 .. +160][o] in 160 VGPRs.
// x rows staged 8 at a time into LDS (f32, float4 loads).
// ---------------------------------------------------------------------------
__global__ __launch_bounds__(256, 2) void scores_kernel(
    const float* __restrict__ x, const float* __restrict__ P,
    float* __restrict__ Wgt)
{
    const int b = blockIdx.y;
    const int s0 = blockIdx.x * 128;
    const int tid = threadIdx.x;
    const int o = tid & 31, c = tid >> 5;
    const int wave = tid >> 6;
    const float scale = 0.07905694150420949f;   // 1/sqrt(160)

    __shared__ float xs[8][QD];       // 40 KB
    __shared__ float red[8][4][OO];   // 4 KB
    __shared__ float sig[8][OO];      // 1 KB

    float p[160];
    {
        const float* Pb = P + b * QD * OO + (c * DH) * OO + o;
#pragma unroll
        for (int i = 0; i < 160; i++) p[i] = Pb[i * OO];
    }

    for (int g = 0; g < 16; g++) {
        __syncthreads();
        // stage 8 rows of x via float4: 8 * 320 chunks
        for (int l = tid; l < 8 * (QD / 4); l += 256) {
            int row = l / (QD / 4), chunk = l % (QD / 4);
            f32x4 v = *(const f32x4*)(x + (size_t)(b * SS + s0 + g * 8 + row) * QD + chunk * 4);
            *(f32x4*)&xs[row][chunk * 4] = v;
        }
        __syncthreads();

        for (int row = 0; row < 8; row++) {
            const float* xr = &xs[row][c * DH];
            float acc = 0.f;
#pragma unroll
            for (int i = 0; i < 160; i++) acc += xr[i] * p[i];
            acc += __shfl_xor(acc, 32);
            if ((tid & 63) < 32) red[row][wave][o] = acc;
        }
        __syncthreads();
        {
            int row = tid >> 5;
            float sc = (red[row][0][o] + red[row][1][o] + red[row][2][o] + red[row][3][o]) * scale;
            sig[row][o] = 1.f / (1.f + __expf(-sc));
        }
        __syncthreads();
        {
            int row = tid >> 5;
            float op0 = 0.f;
#pragma unroll
            for (int h = 0; h < 8; h++) op0 += sig[row][h * 4 + 0] + sig[row][h * 4 + 2];
            op0 = fminf(op0 * 0.125f, 1.f);
            float T = (o & 1) ? (1.f - op0) : 1.f;
            Wgt[(size_t)(b * SS + s0 + g * 8 + row) * OO + o] = T * sig[row][o];
        }
    }
}

// ---------------------------------------------------------------------------
// K4: out[b,s,j] = x[b,s,j] + bout[j] + sum_ht w[b,s,ht] * VW[b,ht,j]
// grid (32 s-tiles of 128, 16 b), 320 thr (QD/4 float4 chunks, 16B/lane).
// Thread keeps VW[b][*][4*tid..4*tid+3] in 128 VGPRs.
// ---------------------------------------------------------------------------
__global__ __launch_bounds__(320) void out_kernel(
    const float* __restrict__ x, const float* __restrict__ bout,
    const float* __restrict__ VW, const float* __restrict__ Wgt,
    float* __restrict__ out)
{
    const int b = blockIdx.y;
    const int s0 = blockIdx.x * 128;
    const int tid = threadIdx.x;

    __shared__ float wbuf[8][OO];

    f32x4 vw[32];
    {
        const float* VWb = VW + (size_t)b * OO * QD + 4 * tid;
#pragma unroll
        for (int ht = 0; ht < 32; ht++) vw[ht] = *(const f32x4*)(VWb + ht * QD);
    }
    f32x4 bo = *(const f32x4*)(bout + 4 * tid);

    for (int g = 0; g < 16; g++) {
        __syncthreads();
        if (tid < 256)
            wbuf[tid >> 5][tid & 31] = Wgt[(size_t)(b * SS + s0 + g * 8 + (tid >> 5)) * OO + (tid & 31)];
        __syncthreads();
        for (int row = 0; row < 8; row++) {
            const size_t roff = (size_t)(b * SS + s0 + g * 8 + row) * QD + 4 * tid;
            f32x4 acc = bo + *(const f32x4*)(x + roff);
#pragma unroll
            for (int ht = 0; ht < 32; ht++) {
                float w = wbuf[row][ht];
                acc += w * vw[ht];
            }
            *(f32x4*)(out + roff) = acc;
        }
    }
}

// ---------------------------------------------------------------------------
extern "C" void kernel_launch(void* const* d_in, const int* in_sizes, int n_in,
                              void* d_out, int out_size, void* d_ws, size_t ws_size,
                              hipStream_t stream) {
    const float* x    = (const float*)d_in[0];
    const float* ctx  = (const float*)d_in[1];
    const float* Wq   = (const float*)d_in[2];
    const float* Wk   = (const float*)d_in[3];
    const float* Ak   = (const float*)d_in[4];
    const float* Bk   = (const float*)d_in[5];
    const float* Wv   = (const float*)d_in[6];
    const float* Av   = (const float*)d_in[7];
    const float* Bv   = (const float*)d_in[8];
    const float* pe   = (const float*)d_in[9];
    const float* Wout = (const float*)d_in[10];
    const float* bout = (const float*)d_in[11];
    float* out = (float*)d_out;

    // Workspace layout (floats): Kf 81920 | Vf 81920 | P 655360 | VW 655360 | Wgt 2097152
    float* ws = (float*)d_ws;
    float* Kf = ws;
    float* Vf = ws + 81920;
    float* P  = ws + 163840;
    float* VW = ws + 819200;
    float* Wg = ws + 1474560;   // total 3,571,712 floats = 14.3 MB

    kv_kernel<<<dim3(5, 4, 16), 256, 0, stream>>>(ctx, pe, Wk, Ak, Bk, Wv, Av, Bv, Kf, Vf);
    pvw_kernel<<<dim3(2, 32, 16), 256, 0, stream>>>(Wq, Wout, Kf, Vf, P, VW);
    scores_kernel<<<dim3(32, 16), 256, 0, stream>>>(x, P, Wg);
    out_kernel<<<dim3(32, 16), 320, 0, stream>>>(x, bout, VW, Wg, out);
}